// Round 8
// baseline (389.978 us; speedup 1.0000x reference)
//
#include <hip/hip_runtime.h>
#include <hip/hip_bf16.h>

// ---------------------------------------------------------------------------
// PolygonPredictionLayer: B=8,P=64,N=512,T=196(->224),S=100(->112),C=256,H=8,dh=32
// R8: fused_cross v3 -- 256-thread blocks (4 waves, wave = 2 heads) so 1 wave/
//     SIMD -> 512-reg budget, no spills (R7 spilled: 8 waves = 2/SIMD = 256 cap).
//     Q persistent per wave (both heads); weights streamed per chunk from L2;
//     K/V/P wave-private LDS; one barrier per chunk; T14 featT prefetch.
//     Rule-#20 fix: staging rotation uses ternary selects, no dynamic array idx.
// ---------------------------------------------------------------------------

typedef __attribute__((ext_vector_type(8))) short bf16x8;
typedef __attribute__((ext_vector_type(4))) float f32x4;

__device__ __forceinline__ float bf2f(ushort u) {
    union { float f; uint u32; } v; v.u32 = ((uint)u) << 16; return v.f;
}
__device__ __forceinline__ ushort f2bf(float f) {
    union { float f; uint u; } v; v.f = f;
    uint r = v.u + 0x7FFF + ((v.u >> 16) & 1);
    return (ushort)(r >> 16);
}
__device__ __forceinline__ f32x4 MFMA(bf16x8 a, bf16x8 b, f32x4 c) {
    return __builtin_amdgcn_mfma_f32_16x16x32_bf16(a, b, c, 0, 0, 0);
}

#define SCALE_DH 0.17677669529663687f  // 1/sqrt(32)

// ---------------- prep: weights+biases -> ws tables, qcp zero ---------------
#define TOTALW (2337 * 256)
#define QCPN   (8 * 8 * 112 * 32)
#define NBIAS  2337

__global__ void prep_kernel(const float* w0, const float* w1_, const float* w2_,
                            const float* w3, const float* w4, const float* w5,
                            const float* w6, const float* w7, const float* w8,
                            const float* w9, const float* w10,
                            const float* b0, const float* b1_, const float* b2_,
                            const float* b3, const float* b4, const float* b5,
                            const float* b6, const float* b7, const float* b8,
                            const float* b9, const float* b10,
                            ushort* wbf, float* bias, ushort* qcp)
{
    for (size_t i = blockIdx.x * blockDim.x + threadIdx.x;
         i < (size_t)TOTALW + QCPN + NBIAS; i += (size_t)gridDim.x * blockDim.x) {
        if (i < TOTALW) {
            int row = (int)(i >> 8), col = (int)(i & 255);
            const float* sp; int base;
            if      (row < 256)  { sp = w0;  base = 0; }
            else if (row < 512)  { sp = w1_; base = 256; }
            else if (row < 768)  { sp = w2_; base = 512; }
            else if (row < 1024) { sp = w3;  base = 768; }
            else if (row < 1280) { sp = w4;  base = 1024; }
            else if (row < 1536) { sp = w5;  base = 1280; }
            else if (row < 1792) { sp = w6;  base = 1536; }
            else if (row < 2048) { sp = w7;  base = 1792; }
            else if (row < 2304) { sp = w8;  base = 2048; }
            else if (row < 2336) { sp = w9;  base = 2304; }
            else                 { sp = w10; base = 2336; }
            wbf[i] = f2bf(sp[(size_t)(row - base) * 256 + col]);
        } else if (i < (size_t)TOTALW + QCPN) {
            qcp[i - TOTALW] = 0;
        } else {
            int idx = (int)(i - TOTALW - QCPN);
            const float* sp; int base;
            if      (idx < 256)  { sp = b0;  base = 0; }
            else if (idx < 512)  { sp = b1_; base = 256; }
            else if (idx < 768)  { sp = b2_; base = 512; }
            else if (idx < 1024) { sp = b3;  base = 768; }
            else if (idx < 1280) { sp = b4;  base = 1024; }
            else if (idx < 1536) { sp = b5;  base = 1280; }
            else if (idx < 1792) { sp = b6;  base = 1536; }
            else if (idx < 2048) { sp = b7;  base = 1792; }
            else if (idx < 2304) { sp = b8;  base = 2048; }
            else if (idx < 2336) { sp = b9;  base = 2304; }
            else                 { sp = b10; base = 2336; }
            bias[idx] = sp[idx - base];
        }
    }
}

// ---------------- generic small GEMM: out = A @ W^T + bias -----------------
template<int ASRC, int GS, int EPI>
__global__ __launch_bounds__(256)
void gemm_rows(const void* Aptr, const ushort* Wall, const float* Ball,
               ushort* Out, int M, int Wrow0, int Brow0, int ldo)
{
    __shared__ ushort As[64 * 40];
    __shared__ ushort Bs[128 * 40];
    int tid = threadIdx.x;
    int lane = tid & 63, w = tid >> 6;
    int lr = lane & 15, lg = lane >> 4;
    int r0 = blockIdx.x * 64;
    int j0 = blockIdx.y * 128;

    f32x4 acc[4][2];
    #pragma unroll
    for (int mt = 0; mt < 4; ++mt)
        #pragma unroll
        for (int nt = 0; nt < 2; ++nt) { f32x4 z = {0.f,0.f,0.f,0.f}; acc[mt][nt] = z; }

    for (int ks = 0; ks < 8; ++ks) {
        int c0 = ks * 32;
        {
            int i = tid >> 2, q = tid & 3;
            int r = r0 + i;
            if (ASRC == 0) {
                uint4 v = make_uint4(0u,0u,0u,0u);
                if (r < M) v = *(const uint4*)((const ushort*)Aptr + (size_t)r * 256 + c0 + q * 8);
                *(uint4*)(&As[i * 40 + q * 8]) = v;
            } else {
                uint u[4] = {0u,0u,0u,0u};
                if (r < M) {
                    int g = r / GS, o = r - g * GS;
                    const float* src = (const float*)Aptr + (size_t)g * 256 * GS + o;
                    #pragma unroll
                    for (int k2 = 0; k2 < 4; ++k2) {
                        ushort a0 = f2bf(src[(size_t)(c0 + q * 8 + 2 * k2)     * GS]);
                        ushort a1 = f2bf(src[(size_t)(c0 + q * 8 + 2 * k2 + 1) * GS]);
                        u[k2] = (uint)a0 | ((uint)a1 << 16);
                    }
                }
                *(uint4*)(&As[i * 40 + q * 8]) = make_uint4(u[0], u[1], u[2], u[3]);
            }
        }
        {
            int jj = tid >> 1, half = tid & 1;
            const ushort* src = Wall + (size_t)(Wrow0 + j0 + jj) * 256 + c0 + half * 16;
            ushort* dst = &Bs[jj * 40 + half * 16];
            *(uint4*)(dst)     = *(const uint4*)(src);
            *(uint4*)(dst + 8) = *(const uint4*)(src + 8);
        }
        __syncthreads();
        bf16x8 bfr[2];
        #pragma unroll
        for (int nt = 0; nt < 2; ++nt)
            bfr[nt] = *(const bf16x8*)(&Bs[(w * 32 + nt * 16 + lr) * 40 + lg * 8]);
        #pragma unroll
        for (int mt = 0; mt < 4; ++mt) {
            bf16x8 afr = *(const bf16x8*)(&As[(mt * 16 + lr) * 40 + lg * 8]);
            acc[mt][0] = MFMA(afr, bfr[0], acc[mt][0]);
            acc[mt][1] = MFMA(afr, bfr[1], acc[mt][1]);
        }
        __syncthreads();
    }
    #pragma unroll
    for (int mt = 0; mt < 4; ++mt) {
        #pragma unroll
        for (int nt = 0; nt < 2; ++nt) {
            int jc = j0 + w * 32 + nt * 16 + lr;
            float bias = Ball[Brow0 + jc];
            #pragma unroll
            for (int rg = 0; rg < 4; ++rg) {
                int r = r0 + mt * 16 + lg * 4 + rg;
                if (r >= M) continue;
                float vv = acc[mt][nt][rg] + bias;
                if (EPI == 0) {
                    Out[(size_t)r * ldo + jc] = f2bf(vv);
                } else {
                    int b = r / 100, s = r - b * 100;
                    int h = jc >> 5, d = jc & 31;
                    Out[(((size_t)(b * 8 + h)) * 112 + s) * 32 + d] = f2bf(vv * SCALE_DH);
                }
            }
        }
    }
}

// ---------------- self-attention (tiny, VALU) ------------------------------
__global__ __launch_bounds__(128)
void self_attn(const ushort* qkv, ushort* sav)
{
    __shared__ float kls[100][33];
    __shared__ float vls[100][33];
    __shared__ float sls[100][101];
    int bh = blockIdx.x; int b = bh >> 3, h = bh & 7;
    int tid = threadIdx.x;
    for (int idx = tid; idx < 100 * 32; idx += 128) {
        int t = idx >> 5, d = idx & 31;
        kls[t][d] = bf2f(qkv[((size_t)(b * 100 + t)) * 768 + 256 + h * 32 + d]);
        vls[t][d] = bf2f(qkv[((size_t)(b * 100 + t)) * 768 + 512 + h * 32 + d]);
    }
    __syncthreads();
    if (tid < 100) {
        int s = tid;
        float q[32];
        #pragma unroll
        for (int d = 0; d < 32; ++d)
            q[d] = bf2f(qkv[((size_t)(b * 100 + s)) * 768 + h * 32 + d]) * SCALE_DH;
        float mx = -1e30f;
        for (int t = 0; t < 100; ++t) {
            float sc = 0.f;
            #pragma unroll
            for (int d = 0; d < 32; ++d) sc += q[d] * kls[t][d];
            sls[s][t] = sc; mx = fmaxf(mx, sc);
        }
        float sum = 0.f;
        for (int t = 0; t < 100; ++t) {
            float p = __expf(sls[s][t] - mx);
            sls[s][t] = p; sum += p;
        }
        float inv = 1.f / sum;
        float acc2[32];
        #pragma unroll
        for (int d = 0; d < 32; ++d) acc2[d] = 0.f;
        for (int t = 0; t < 100; ++t) {
            float pv = sls[s][t];
            #pragma unroll
            for (int d = 0; d < 32; ++d) acc2[d] += pv * vls[t][d];
        }
        #pragma unroll
        for (int d = 0; d < 32; ++d)
            sav[((size_t)(b * 100 + s)) * 256 + h * 32 + d] = f2bf(acc2[d] * inv);
    }
}

// ---------------- fused cross: KV-proj + flash attn + heads ----------------
// block 256 (4 waves, wave = heads 2w,2w+1), one block per proposal (grid 512).
// LDS main (79872 B): featT dbuf 2x[32][264] @0/@16896 | Kp[8][32][40] @33792
// | Vp[8][32][40] @54272 | Pp[4][16][40] @74752.
// Epilogue overlay: OL[112][264] @0 | hbar @59136 | scb @60160 | O2[112][264] @60608.
__global__ __launch_bounds__(256, 1)
void fused_cross(const float* features, const ushort* qcp, const ushort* Wall,
                 const float* Ball, float* outp)
{
    __shared__ char smem[119808];
    ushort* featT0 = (ushort*)smem;
    ushort* featT1 = (ushort*)(smem + 16896);
    ushort* Kp  = (ushort*)(smem + 33792);
    ushort* Vp  = (ushort*)(smem + 54272);
    ushort* Pp  = (ushort*)(smem + 74752);
    ushort* OL  = (ushort*)smem;
    float* hbar = (float*)(smem + 59136);
    float* scb  = (float*)(smem + 60160);
    ushort* O2  = (ushort*)(smem + 60608);

    int tid = threadIdx.x;
    int lane = tid & 63; int w = tid >> 6;             // wave 0..3
    int lr = lane & 15, lg = lane >> 4;
    int n = blockIdx.x; int b = n >> 6;
    const float* fb = features + (size_t)n * 256 * 196;
    int hA = 2 * w, hB = 2 * w + 1;
    ushort* KA = Kp + hA * 1280; ushort* KB = Kp + hB * 1280;   // [32 t][40] d
    ushort* VA = Vp + hA * 1280; ushort* VB = Vp + hB * 1280;   // [32 cl][40] t
    ushort* Pw = Pp + w * 640;                                   // [16 s][40] t

    // persistent Q fragments for both heads (L2 -> VGPR once)
    bf16x8 qfA[7], qfB[7];
    #pragma unroll
    for (int mt = 0; mt < 7; ++mt) {
        qfA[mt] = *(const bf16x8*)(qcp + ((((size_t)(b * 8 + hA)) * 112 + mt * 16 + lr) * 32 + lg * 8));
        qfB[mt] = *(const bf16x8*)(qcp + ((((size_t)(b * 8 + hB)) * 112 + mt * 16 + lr) * 32 + lg * 8));
    }

    bf16x8 ones;
    #pragma unroll
    for (int j = 0; j < 8; ++j) ones[j] = (short)0x3F80;

    f32x4 oA[7][2], lA[7], oB[7][2], lB[7];
    #pragma unroll
    for (int mt = 0; mt < 7; ++mt) {
        f32x4 z = {0.f,0.f,0.f,0.f};
        oA[mt][0] = z; oA[mt][1] = z; lA[mt] = z;
        oB[mt][0] = z; oB[mt][1] = z; lB[mt] = z;
    }

    // stage chunk 0 into featT0 (2048 float4; 256 thr x 8)
    #pragma unroll
    for (int i = 0; i < 8; ++i) {
        int idx = tid + i * 256;
        int c = idx >> 3, tq = idx & 7;
        float4 v = *(const float4*)(fb + (size_t)c * 196 + tq * 4);
        #pragma unroll
        for (int k = 0; k < 4; ++k) {
            int j = (k + tq) & 3;   // rotate write order; ternary select (no scratch)
            float e = (j == 0) ? v.x : (j == 1) ? v.y : (j == 2) ? v.z : v.w;
            featT0[(tq * 4 + j) * 264 + c] = f2bf(e);
        }
    }
    __syncthreads();

    // per-chunk KV projection for one head (weights streamed from L2)
    auto kv_pass = [&](int h, ushort* Kh, ushort* Vh, const ushort* Fc) {
        const ushort* wkb = Wall + (size_t)(1280 + h * 32 + lr) * 256 + lg * 8;
        const ushort* wvb = Wall + (size_t)(1536 + h * 32 + lr) * 256 + lg * 8;
        float bk0 = Ball[1280 + h * 32 + lr];
        float bk1 = Ball[1296 + h * 32 + lr];
        float bv0 = Ball[1536 + h * 32 + lr];
        float bv1 = Ball[1552 + h * 32 + lr];
        f32x4 aK[2][2], aV[2][2];
        #pragma unroll
        for (int mt = 0; mt < 2; ++mt)
            #pragma unroll
            for (int nt = 0; nt < 2; ++nt) {
                f32x4 z = {0.f,0.f,0.f,0.f}; aK[mt][nt] = z; aV[mt][nt] = z;
            }
        #pragma unroll
        for (int ks = 0; ks < 8; ++ks) {
            bf16x8 wk0 = *(const bf16x8*)(wkb + ks * 32);
            bf16x8 wk1 = *(const bf16x8*)(wkb + 16 * 256 + ks * 32);
            bf16x8 wv0 = *(const bf16x8*)(wvb + ks * 32);
            bf16x8 wv1 = *(const bf16x8*)(wvb + 16 * 256 + ks * 32);
            #pragma unroll
            for (int mt = 0; mt < 2; ++mt) {
                bf16x8 af = *(const bf16x8*)(&Fc[(mt * 16 + lr) * 264 + ks * 32 + lg * 8]);
                aK[mt][0] = MFMA(af, wk0, aK[mt][0]);
                aK[mt][1] = MFMA(af, wk1, aK[mt][1]);
                aV[mt][0] = MFMA(af, wv0, aV[mt][0]);
                aV[mt][1] = MFMA(af, wv1, aV[mt][1]);
            }
        }
        #pragma unroll
        for (int mt = 0; mt < 2; ++mt)
            #pragma unroll
            for (int rg = 0; rg < 4; ++rg) {
                int tl = mt * 16 + lg * 4 + rg;
                Kh[tl * 40 + lr]      = f2bf(aK[mt][0][rg] + bk0);
                Kh[tl * 40 + 16 + lr] = f2bf(aK[mt][1][rg] + bk1);
            }
        #pragma unroll
        for (int mt = 0; mt < 2; ++mt)
            #pragma unroll
            for (int nt = 0; nt < 2; ++nt) {
                float bv_ = nt ? bv1 : bv0;
                int tb = mt * 16 + lg * 4;
                uint v01 = (uint)f2bf(aV[mt][nt][0] + bv_) | ((uint)f2bf(aV[mt][nt][1] + bv_) << 16);
                uint v23 = (uint)f2bf(aV[mt][nt][2] + bv_) | ((uint)f2bf(aV[mt][nt][3] + bv_) << 16);
                *(uint*)(Vh + (nt * 16 + lr) * 40 + tb)     = v01;
                *(uint*)(Vh + (nt * 16 + lr) * 40 + tb + 2) = v23;
            }
    };

    // per-chunk attention for one head (K/V/P wave-private)
    auto attn_pass = [&](const bf16x8 (&qf)[7], const ushort* Kh, const ushort* Vh,
                         f32x4 (&oa)[7][2], f32x4 (&la)[7], int t0) {
        bf16x8 bk0 = *(const bf16x8*)(&Kh[lr * 40 + lg * 8]);
        bf16x8 bk1 = *(const bf16x8*)(&Kh[(16 + lr) * 40 + lg * 8]);
        bf16x8 bv0 = *(const bf16x8*)(&Vh[lr * 40 + lg * 8]);
        bf16x8 bv1 = *(const bf16x8*)(&Vh[(16 + lr) * 40 + lg * 8]);
        bool mask0 = (t0 + lr)      >= 196;
        bool mask1 = (t0 + 16 + lr) >= 196;
        #pragma unroll
        for (int mt = 0; mt < 7; ++mt) {
            f32x4 z = {0.f,0.f,0.f,0.f};
            f32x4 s0 = MFMA(qf[mt], bk0, z);
            f32x4 s1 = MFMA(qf[mt], bk1, z);
            #pragma unroll
            for (int r = 0; r < 4; ++r) {
                float p0 = mask0 ? 0.f : __expf(s0[r]);
                float p1 = mask1 ? 0.f : __expf(s1[r]);
                Pw[(lg * 4 + r) * 40 + lr]      = f2bf(p0);
                Pw[(lg * 4 + r) * 40 + 16 + lr] = f2bf(p1);
            }
            bf16x8 pf = *(const bf16x8*)(&Pw[lr * 40 + lg * 8]);
            oa[mt][0] = MFMA(pf, bv0, oa[mt][0]);
            oa[mt][1] = MFMA(pf, bv1, oa[mt][1]);
            la[mt]    = MFMA(pf, ones, la[mt]);
        }
    };

    float4 pre[8];
    for (int ch = 0; ch < 7; ++ch) {
        ushort* Fc = (ch & 1) ? featT1 : featT0;
        ushort* Fn = (ch & 1) ? featT0 : featT1;
        int t0 = ch * 32;

        kv_pass(hA, KA, VA, Fc);
        kv_pass(hB, KB, VB, Fc);

        // T14: issue next chunk's feature loads (hidden under attention)
        if (ch < 6) {
            int t0n = t0 + 32;
            #pragma unroll
            for (int i = 0; i < 8; ++i) {
                int idx = tid + i * 256;
                int c = idx >> 3, tq = idx & 7;
                int tg = t0n + tq * 4;
                float4 z = {0.f,0.f,0.f,0.f};
                pre[i] = (tg < 196) ? *(const float4*)(fb + (size_t)c * 196 + tg) : z;
            }
        }

        attn_pass(qfA, KA, VA, oA, lA, t0);
        attn_pass(qfB, KB, VB, oB, lB, t0);

        if (ch < 6) {
            #pragma unroll
            for (int i = 0; i < 8; ++i) {
                int idx = tid + i * 256;
                int c = idx >> 3, tq = idx & 7;
                #pragma unroll
                for (int k = 0; k < 4; ++k) {
                    int j = (k + tq) & 3;
                    float e = (j == 0) ? pre[i].x : (j == 1) ? pre[i].y
                            : (j == 2) ? pre[i].z : pre[i].w;
                    Fn[(tq * 4 + j) * 264 + c] = f2bf(e);
                }
            }
        }
        __syncthreads();   // featT[next] ready; all waves done with this chunk
    }

    // ---- epilogue: normalized O -> OL[112][264] (both heads) ----
    #pragma unroll
    for (int mt = 0; mt < 7; ++mt) {
        #pragma unroll
        for (int r = 0; r < 4; ++r) {
            int srow = mt * 16 + lg * 4 + r;
            float invA = 1.f / lA[mt][r];
            float invB = 1.f / lB[mt][r];
            OL[srow * 264 + hA * 32 + lr]      = f2bf(oA[mt][0][r] * invA);
            OL[srow * 264 + hA * 32 + 16 + lr] = f2bf(oA[mt][1][r] * invA);
            OL[srow * 264 + hB * 32 + lr]      = f2bf(oB[mt][0][r] * invB);
            OL[srow * 264 + hB * 32 + 16 + lr] = f2bf(oB[mt][1][r] * invB);
        }
    }
    __syncthreads();

    int jbase = w * 64;   // wave covers 64 output cols in epilogue GEMMs

    // o2 = OL @ wo_c^T + bo_c
    {
        f32x4 a2[7][4];
        #pragma unroll
        for (int mt = 0; mt < 7; ++mt)
            #pragma unroll
            for (int nt = 0; nt < 4; ++nt) { f32x4 z = {0.f,0.f,0.f,0.f}; a2[mt][nt] = z; }
        for (int ks = 0; ks < 8; ++ks) {
            int c0 = ks * 32;
            bf16x8 bw[4];
            #pragma unroll
            for (int nt = 0; nt < 4; ++nt)
                bw[nt] = *(const bf16x8*)(Wall + (size_t)(1792 + jbase + nt * 16 + lr) * 256 + c0 + lg * 8);
            #pragma unroll
            for (int mt = 0; mt < 7; ++mt) {
                bf16x8 af = *(const bf16x8*)(&OL[(mt * 16 + lr) * 264 + c0 + lg * 8]);
                #pragma unroll
                for (int nt = 0; nt < 4; ++nt)
                    a2[mt][nt] = MFMA(af, bw[nt], a2[mt][nt]);
            }
        }
        #pragma unroll
        for (int mt = 0; mt < 7; ++mt)
            #pragma unroll
            for (int nt = 0; nt < 4; ++nt) {
                float bias = Ball[1792 + jbase + nt * 16 + lr];
                #pragma unroll
                for (int r = 0; r < 4; ++r) {
                    int srow = mt * 16 + lg * 4 + r;
                    O2[srow * 264 + jbase + nt * 16 + lr] = f2bf(a2[mt][nt][r] + bias);
                }
            }
    }
    __syncthreads();

    // h1 = relu(O2 @ w1^T + b1) -> OL
    {
        f32x4 a2[7][4];
        #pragma unroll
        for (int mt = 0; mt < 7; ++mt)
            #pragma unroll
            for (int nt = 0; nt < 4; ++nt) { f32x4 z = {0.f,0.f,0.f,0.f}; a2[mt][nt] = z; }
        for (int ks = 0; ks < 8; ++ks) {
            int c0 = ks * 32;
            bf16x8 bw[4];
            #pragma unroll
            for (int nt = 0; nt < 4; ++nt)
                bw[nt] = *(const bf16x8*)(Wall + (size_t)(2048 + jbase + nt * 16 + lr) * 256 + c0 + lg * 8);
            #pragma unroll
            for (int mt = 0; mt < 7; ++mt) {
                bf16x8 af = *(const bf16x8*)(&O2[(mt * 16 + lr) * 264 + c0 + lg * 8]);
                #pragma unroll
                for (int nt = 0; nt < 4; ++nt)
                    a2[mt][nt] = MFMA(af, bw[nt], a2[mt][nt]);
            }
        }
        __syncthreads();   // all OL reads (oproj phase) complete before overwrite
        #pragma unroll
        for (int mt = 0; mt < 7; ++mt)
            #pragma unroll
            for (int nt = 0; nt < 4; ++nt) {
                float bias = Ball[2048 + jbase + nt * 16 + lr];
                #pragma unroll
                for (int r = 0; r < 4; ++r) {
                    int srow = mt * 16 + lg * 4 + r;
                    float v = a2[mt][nt][r] + bias;
                    v = v > 0.f ? v : 0.f;
                    OL[srow * 264 + jbase + nt * 16 + lr] = f2bf(v);
                }
            }
    }
    __syncthreads();

    // hbar[c] = mean_s<100 h1[s][c];  score partials from O2
    {
        float s = 0.f;
        for (int srow = 0; srow < 100; ++srow) s += bf2f(OL[srow * 264 + tid]);
        hbar[tid] = s * 0.01f;
    }
    if (tid < 100) {
        float s = 0.f;
        for (int c2 = 0; c2 < 256; ++c2)
            s += bf2f(O2[tid * 264 + c2]) * bf2f(Wall[(size_t)2336 * 256 + c2]);
        s += Ball[2336];
        scb[tid] = 1.f / (1.f + __expf(-s));
    }
    __syncthreads();
    if (tid < 32) {
        float s = 0.f;
        for (int c2 = 0; c2 < 256; ++c2)
            s += hbar[c2] * bf2f(Wall[(size_t)(2304 + tid) * 256 + c2]);
        s += Ball[2304 + tid];
        outp[(size_t)n * 32 + tid] = s;
    }
    if (tid == 64) {
        float s = 0.f;
        for (int i2 = 0; i2 < 100; ++i2) s += scb[i2];
        outp[16384 + n] = s * 0.01f;
    }
}

// ---------------------------------------------------------------------------
extern "C" void kernel_launch(void* const* d_in, const int* in_sizes, int n_in,
                              void* d_out, int out_size, void* d_ws, size_t ws_size,
                              hipStream_t stream)
{
    const float* features = (const float*)d_in[0];
    const float* qfeat    = (const float*)d_in[1];
    char* ws = (char*)d_ws;

    ushort* wbf  = (ushort*)ws;                    //  2337*256 bf16
    float*  bias = (float*)(ws + 1196544);         //  2337 f32
    ushort* qkv  = (ushort*)(ws + 1206016);        //  800*768
    ushort* sav  = (ushort*)(ws + 2434816);        //  800*256
    ushort* osb  = (ushort*)(ws + 2844416);        //  800*256
    ushort* qcp  = (ushort*)(ws + 3254016);        //  8*8*112*32

    prep_kernel<<<dim3(512), dim3(256), 0, stream>>>(
        (const float*)d_in[2], (const float*)d_in[3], (const float*)d_in[4],
        (const float*)d_in[8], (const float*)d_in[10], (const float*)d_in[11],
        (const float*)d_in[12], (const float*)d_in[16], (const float*)d_in[18],
        (const float*)d_in[20], (const float*)d_in[22],
        (const float*)d_in[5], (const float*)d_in[6], (const float*)d_in[7],
        (const float*)d_in[9], (const float*)d_in[13], (const float*)d_in[14],
        (const float*)d_in[15], (const float*)d_in[17], (const float*)d_in[19],
        (const float*)d_in[21], (const float*)d_in[23],
        wbf, bias, qcp);

    // self-attention chain
    gemm_rows<1, 100, 0><<<dim3(13, 6), dim3(256), 0, stream>>>(
        qfeat, wbf, bias, qkv, 800, 0, 0, 768);
    self_attn<<<dim3(64), dim3(128), 0, stream>>>(qkv, sav);
    gemm_rows<0, 1, 0><<<dim3(13, 2), dim3(256), 0, stream>>>(
        sav, wbf, bias, osb, 800, 768, 768, 256);
    gemm_rows<0, 1, 1><<<dim3(13, 2), dim3(256), 0, stream>>>(
        osb, wbf, bias, qcp, 800, 1024, 1024, 0);

    // fused cross-attention + heads (K/V never touch HBM)
    fused_cross<<<dim3(512), dim3(256), 0, stream>>>(
        features, qcp, wbf, bias, (float*)d_out);
}

// Round 9
// 369.307 us; speedup vs baseline: 1.0560x; 1.0560x over previous
//
#include <hip/hip_runtime.h>
#include <hip/hip_bf16.h>

// ---------------------------------------------------------------------------
// PolygonPredictionLayer: B=8,P=64,N=512,T=196(->224),S=100(->112),C=256,H=8,dh=32
// R9: back to split (R5=230us best). kvproj v6: A=weights (global vector),
//     B=features staged RAW f32 [c][114] in LDS (no transpose, no cvt on store;
//     cvt via v_cvt_pk on read). Grid (n,2), K in two 128-c LDS passes, 3
//     barriers/block, acc 112 AGPR -> no spill. attn_fuse v2: K/V fragments
//     loaded DIRECTLY from global (kc t-major / vc c-major are frag-contiguous),
//     zero barriers in main loop, only wave-private P in LDS.
// ---------------------------------------------------------------------------

typedef __attribute__((ext_vector_type(8))) short bf16x8;
typedef __attribute__((ext_vector_type(4))) float f32x4;

__device__ __forceinline__ float bf2f(ushort u) {
    union { float f; uint u32; } v; v.u32 = ((uint)u) << 16; return v.f;
}
__device__ __forceinline__ ushort f2bf(float f) {
    union { float f; uint u; } v; v.f = f;
    uint r = v.u + 0x7FFF + ((v.u >> 16) & 1);
    return (ushort)(r >> 16);
}
__device__ __forceinline__ uint pk2(float a, float b) {
    __hip_bfloat162 h = __float22bfloat162_rn(make_float2(a, b));
    union { __hip_bfloat162 h2; uint u; } c; c.h2 = h; return c.u;
}
__device__ __forceinline__ f32x4 MFMA(bf16x8 a, bf16x8 b, f32x4 c) {
    return __builtin_amdgcn_mfma_f32_16x16x32_bf16(a, b, c, 0, 0, 0);
}

#define SCALE_DH 0.17677669529663687f  // 1/sqrt(32)

// ---------------- prep: weights+biases -> ws tables, qcp zero ---------------
#define TOTALW (2337 * 256)
#define QCPN   (8 * 8 * 112 * 32)
#define NBIAS  2337

__global__ void prep_kernel(const float* w0, const float* w1_, const float* w2_,
                            const float* w3, const float* w4, const float* w5,
                            const float* w6, const float* w7, const float* w8,
                            const float* w9, const float* w10,
                            const float* b0, const float* b1_, const float* b2_,
                            const float* b3, const float* b4, const float* b5,
                            const float* b6, const float* b7, const float* b8,
                            const float* b9, const float* b10,
                            ushort* wbf, float* bias, ushort* qcp)
{
    for (size_t i = blockIdx.x * blockDim.x + threadIdx.x;
         i < (size_t)TOTALW + QCPN + NBIAS; i += (size_t)gridDim.x * blockDim.x) {
        if (i < TOTALW) {
            int row = (int)(i >> 8), col = (int)(i & 255);
            const float* sp; int base;
            if      (row < 256)  { sp = w0;  base = 0; }
            else if (row < 512)  { sp = w1_; base = 256; }
            else if (row < 768)  { sp = w2_; base = 512; }
            else if (row < 1024) { sp = w3;  base = 768; }
            else if (row < 1280) { sp = w4;  base = 1024; }
            else if (row < 1536) { sp = w5;  base = 1280; }
            else if (row < 1792) { sp = w6;  base = 1536; }
            else if (row < 2048) { sp = w7;  base = 1792; }
            else if (row < 2304) { sp = w8;  base = 2048; }
            else if (row < 2336) { sp = w9;  base = 2304; }
            else                 { sp = w10; base = 2336; }
            wbf[i] = f2bf(sp[(size_t)(row - base) * 256 + col]);
        } else if (i < (size_t)TOTALW + QCPN) {
            qcp[i - TOTALW] = 0;
        } else {
            int idx = (int)(i - TOTALW - QCPN);
            const float* sp; int base;
            if      (idx < 256)  { sp = b0;  base = 0; }
            else if (idx < 512)  { sp = b1_; base = 256; }
            else if (idx < 768)  { sp = b2_; base = 512; }
            else if (idx < 1024) { sp = b3;  base = 768; }
            else if (idx < 1280) { sp = b4;  base = 1024; }
            else if (idx < 1536) { sp = b5;  base = 1280; }
            else if (idx < 1792) { sp = b6;  base = 1536; }
            else if (idx < 2048) { sp = b7;  base = 1792; }
            else if (idx < 2304) { sp = b8;  base = 2048; }
            else if (idx < 2336) { sp = b9;  base = 2304; }
            else                 { sp = b10; base = 2336; }
            bias[idx] = sp[idx - base];
        }
    }
}

// ---------------- generic small GEMM: out = A @ W^T + bias -----------------
template<int ASRC, int GS, int EPI>
__global__ __launch_bounds__(256)
void gemm_rows(const void* Aptr, const ushort* Wall, const float* Ball,
               ushort* Out, int M, int Wrow0, int Brow0, int ldo)
{
    __shared__ ushort As[64 * 40];
    __shared__ ushort Bs[128 * 40];
    int tid = threadIdx.x;
    int lane = tid & 63, w = tid >> 6;
    int lr = lane & 15, lg = lane >> 4;
    int r0 = blockIdx.x * 64;
    int j0 = blockIdx.y * 128;

    f32x4 acc[4][2];
    #pragma unroll
    for (int mt = 0; mt < 4; ++mt)
        #pragma unroll
        for (int nt = 0; nt < 2; ++nt) { f32x4 z = {0.f,0.f,0.f,0.f}; acc[mt][nt] = z; }

    for (int ks = 0; ks < 8; ++ks) {
        int c0 = ks * 32;
        {
            int i = tid >> 2, q = tid & 3;
            int r = r0 + i;
            if (ASRC == 0) {
                uint4 v = make_uint4(0u,0u,0u,0u);
                if (r < M) v = *(const uint4*)((const ushort*)Aptr + (size_t)r * 256 + c0 + q * 8);
                *(uint4*)(&As[i * 40 + q * 8]) = v;
            } else {
                uint u[4] = {0u,0u,0u,0u};
                if (r < M) {
                    int g = r / GS, o = r - g * GS;
                    const float* src = (const float*)Aptr + (size_t)g * 256 * GS + o;
                    #pragma unroll
                    for (int k2 = 0; k2 < 4; ++k2) {
                        ushort a0 = f2bf(src[(size_t)(c0 + q * 8 + 2 * k2)     * GS]);
                        ushort a1 = f2bf(src[(size_t)(c0 + q * 8 + 2 * k2 + 1) * GS]);
                        u[k2] = (uint)a0 | ((uint)a1 << 16);
                    }
                }
                *(uint4*)(&As[i * 40 + q * 8]) = make_uint4(u[0], u[1], u[2], u[3]);
            }
        }
        {
            int jj = tid >> 1, half = tid & 1;
            const ushort* src = Wall + (size_t)(Wrow0 + j0 + jj) * 256 + c0 + half * 16;
            ushort* dst = &Bs[jj * 40 + half * 16];
            *(uint4*)(dst)     = *(const uint4*)(src);
            *(uint4*)(dst + 8) = *(const uint4*)(src + 8);
        }
        __syncthreads();
        bf16x8 bfr[2];
        #pragma unroll
        for (int nt = 0; nt < 2; ++nt)
            bfr[nt] = *(const bf16x8*)(&Bs[(w * 32 + nt * 16 + lr) * 40 + lg * 8]);
        #pragma unroll
        for (int mt = 0; mt < 4; ++mt) {
            bf16x8 afr = *(const bf16x8*)(&As[(mt * 16 + lr) * 40 + lg * 8]);
            acc[mt][0] = MFMA(afr, bfr[0], acc[mt][0]);
            acc[mt][1] = MFMA(afr, bfr[1], acc[mt][1]);
        }
        __syncthreads();
    }
    #pragma unroll
    for (int mt = 0; mt < 4; ++mt) {
        #pragma unroll
        for (int nt = 0; nt < 2; ++nt) {
            int jc = j0 + w * 32 + nt * 16 + lr;
            float bias = Ball[Brow0 + jc];
            #pragma unroll
            for (int rg = 0; rg < 4; ++rg) {
                int r = r0 + mt * 16 + lg * 4 + rg;
                if (r >= M) continue;
                float vv = acc[mt][nt][rg] + bias;
                if (EPI == 0) {
                    Out[(size_t)r * ldo + jc] = f2bf(vv);
                } else {
                    int b = r / 100, s = r - b * 100;
                    int h = jc >> 5, d = jc & 31;
                    Out[(((size_t)(b * 8 + h)) * 112 + s) * 32 + d] = f2bf(vv * SCALE_DH);
                }
            }
        }
    }
}

// ---------------- self-attention (tiny, VALU) ------------------------------
__global__ __launch_bounds__(128)
void self_attn(const ushort* qkv, ushort* sav)
{
    __shared__ float kls[100][33];
    __shared__ float vls[100][33];
    __shared__ float sls[100][101];
    int bh = blockIdx.x; int b = bh >> 3, h = bh & 7;
    int tid = threadIdx.x;
    for (int idx = tid; idx < 100 * 32; idx += 128) {
        int t = idx >> 5, d = idx & 31;
        kls[t][d] = bf2f(qkv[((size_t)(b * 100 + t)) * 768 + 256 + h * 32 + d]);
        vls[t][d] = bf2f(qkv[((size_t)(b * 100 + t)) * 768 + 512 + h * 32 + d]);
    }
    __syncthreads();
    if (tid < 100) {
        int s = tid;
        float q[32];
        #pragma unroll
        for (int d = 0; d < 32; ++d)
            q[d] = bf2f(qkv[((size_t)(b * 100 + s)) * 768 + h * 32 + d]) * SCALE_DH;
        float mx = -1e30f;
        for (int t = 0; t < 100; ++t) {
            float sc = 0.f;
            #pragma unroll
            for (int d = 0; d < 32; ++d) sc += q[d] * kls[t][d];
            sls[s][t] = sc; mx = fmaxf(mx, sc);
        }
        float sum = 0.f;
        for (int t = 0; t < 100; ++t) {
            float p = __expf(sls[s][t] - mx);
            sls[s][t] = p; sum += p;
        }
        float inv = 1.f / sum;
        float acc2[32];
        #pragma unroll
        for (int d = 0; d < 32; ++d) acc2[d] = 0.f;
        for (int t = 0; t < 100; ++t) {
            float pv = sls[s][t];
            #pragma unroll
            for (int d = 0; d < 32; ++d) acc2[d] += pv * vls[t][d];
        }
        #pragma unroll
        for (int d = 0; d < 32; ++d)
            sav[((size_t)(b * 100 + s)) * 256 + h * 32 + d] = f2bf(acc2[d] * inv);
    }
}

// ---------------- kvproj v6: kc[n][224][256] t-major, vc[n][256][224] ------
// grid (cnt, 2 th), block 512 (8 waves). A = weights (global vector loads),
// B = features RAW f32 in LDS [128 c][114 t-pad] (two K-halves, 3 barriers).
// Wave w owns couts [32w,32w+32) of K and of V (4 m-tiles), 7 t-tiles.
__global__ __launch_bounds__(512, 2)
void kvproj(const float* features, const ushort* Wall, const float* Ball,
            ushort* kc, ushort* vc, int n_base)
{
    __shared__ float Fs[128 * 114];
    int tid = threadIdx.x;
    int lane = tid & 63, w = tid >> 6;
    int lr = lane & 15, lg = lane >> 4;
    int nl = blockIdx.x;
    int n  = n_base + nl;
    int th = blockIdx.y;
    int t0b = th * 112;
    const float* fb = features + (size_t)n * 256 * 196;

    f32x4 acc[7][4];
    #pragma unroll
    for (int tt = 0; tt < 7; ++tt)
        #pragma unroll
        for (int m = 0; m < 4; ++m) { f32x4 z = {0.f,0.f,0.f,0.f}; acc[tt][m] = z; }

    for (int cs = 0; cs < 2; ++cs) {
        if (cs) __syncthreads();           // prior-half Fs reads complete
        // stage Fs[cl][2tq] = fb[(cs*128+cl)*196 + t0b + 2tq]  (raw f32, float2)
        #pragma unroll
        for (int i = 0; i < 14; ++i) {
            int idx = i * 512 + tid;       // 0..7167 = 128 c * 56 tq
            int cl = idx / 56, tq = idx - cl * 56;
            int t = t0b + tq * 2;
            float2 v = make_float2(0.f, 0.f);
            if (t < 196) v = *(const float2*)(fb + (size_t)(cs * 128 + cl) * 196 + t);
            *(float2*)(&Fs[cl * 114 + tq * 2]) = v;
        }
        __syncthreads();
        // A-frags (weights) for this K-half: 4 m-tiles x 4 ksl, from L2
        bf16x8 af[4][4];
        #pragma unroll
        for (int m = 0; m < 4; ++m) {
            int row = ((m < 2) ? 1280 : 1536) + w * 32 + (m & 1) * 16 + lr;
            #pragma unroll
            for (int ksl = 0; ksl < 4; ++ksl)
                af[m][ksl] = *(const bf16x8*)(Wall + (size_t)row * 256 + cs * 128 + ksl * 32 + lg * 8);
        }
        #pragma unroll
        for (int tt = 0; tt < 7; ++tt) {
            #pragma unroll
            for (int ksl = 0; ksl < 4; ++ksl) {
                const float* bp = &Fs[(ksl * 32 + lg * 8) * 114 + tt * 16 + lr];
                union { uint4 q; bf16x8 v; } bu;
                bu.q.x = pk2(bp[0],       bp[114]);
                bu.q.y = pk2(bp[2 * 114], bp[3 * 114]);
                bu.q.z = pk2(bp[4 * 114], bp[5 * 114]);
                bu.q.w = pk2(bp[6 * 114], bp[7 * 114]);
                #pragma unroll
                for (int m = 0; m < 4; ++m)
                    acc[tt][m] = MFMA(af[m][ksl], bu.v, acc[tt][m]);
            }
        }
    }

    // write-out: D row = cout_local (lg*4+rg), col = t (lr)
    #pragma unroll
    for (int tt = 0; tt < 7; ++tt) {
        int tloc = t0b + tt * 16 + lr;
        #pragma unroll
        for (int m = 0; m < 4; ++m) {
            int cout0 = w * 32 + (m & 1) * 16 + lg * 4;
            if (m < 2) {   // kc t-major: 4 consecutive couts -> ushort4
                float4 bk4 = *(const float4*)(Ball + 1280 + cout0);
                ushort4 o;
                o.x = f2bf(acc[tt][m][0] + bk4.x);
                o.y = f2bf(acc[tt][m][1] + bk4.y);
                o.z = f2bf(acc[tt][m][2] + bk4.z);
                o.w = f2bf(acc[tt][m][3] + bk4.w);
                *(ushort4*)(kc + ((size_t)nl * 224 + tloc) * 256 + cout0) = o;
            } else {       // vc c-major: scalar per cout
                #pragma unroll
                for (int rg = 0; rg < 4; ++rg) {
                    int cout = cout0 + rg;
                    vc[((size_t)nl * 256 + cout) * 224 + tloc] =
                        f2bf(acc[tt][m][rg] + Ball[1536 + cout]);
                }
            }
        }
    }
}

// ---------------- attn_fuse v2: barrier-free main loop ---------------------
// block 512 (8 waves, wave = head). K/V fragments loaded DIRECTLY from global
// (kc t-major, vc c-major are frag-contiguous); double-buffered in registers.
// LDS: Pp[8][16][40] @71680 (main loop only). Epilogue overlay: OL[112][264]
// @0 | hbar @59392 | scb @60416 | O2[112][264] @71680.
__global__ __launch_bounds__(512, 2)
void attn_fuse(const ushort* qcp, const ushort* kc, const ushort* vc,
               const ushort* Wall, const float* Ball, float* outp, int n_base)
{
    __shared__ char smem[130816];
    ushort* OL  = (ushort*)smem;
    float* hbar = (float*)(smem + 59392);
    float* scb  = (float*)(smem + 60416);
    ushort* O2  = (ushort*)(smem + 71680);
    ushort* Pp  = (ushort*)(smem + 71680);   // disjoint in time from O2

    int tid = threadIdx.x;
    int lane = tid & 63; int w = tid >> 6;             // w = head
    int lr = lane & 15, lg = lane >> 4;
    int nl = blockIdx.x; int n = n_base + nl;
    int b = n >> 6;
    const ushort* kcn = kc + (size_t)nl * 224 * 256;
    const ushort* vcn = vc + (size_t)nl * 256 * 224;
    ushort* Pw = Pp + w * 640;                          // [16 s][40 t]

    bf16x8 qf[7];
    #pragma unroll
    for (int mt = 0; mt < 7; ++mt)
        qf[mt] = *(const bf16x8*)(qcp + ((((size_t)(b * 8 + w)) * 112 + mt * 16 + lr) * 32 + lg * 8));

    bf16x8 ones;
    #pragma unroll
    for (int j = 0; j < 8; ++j) ones[j] = (short)0x3F80;

    f32x4 o_acc[7][2], l_acc[7];
    #pragma unroll
    for (int mt = 0; mt < 7; ++mt) {
        f32x4 z = {0.f,0.f,0.f,0.f};
        o_acc[mt][0] = z; o_acc[mt][1] = z; l_acc[mt] = z;
    }

    // fragment addresses (per chunk t0):
    //  bk(sub): kcn[(t0 + sub*16 + lr)*256 + w*32 + lg*8]   (K[t][d], 8 contig d)
    //  bv(sub): vcn[(w*32 + sub*16 + lr)*224 + t0 + lg*8]   (V^T[c][t], 8 contig t)
    const ushort* kbase = kcn + (size_t)lr * 256 + w * 32 + lg * 8;
    const ushort* vbase = vcn + ((size_t)(w * 32 + lr)) * 224 + lg * 8;

    bf16x8 ck0, ck1, cv0, cv1;
    ck0 = *(const bf16x8*)(kbase);
    ck1 = *(const bf16x8*)(kbase + 16 * 256);
    cv0 = *(const bf16x8*)(vbase);
    cv1 = *(const bf16x8*)(vbase + 16 * 224);

    for (int ch = 0; ch < 7; ++ch) {
        int t0 = ch * 32;
        bf16x8 nk0, nk1, nv0, nv1;
        if (ch < 6) {   // T14: next chunk's fragments issued before compute
            int t0n = t0 + 32;
            nk0 = *(const bf16x8*)(kbase + (size_t)t0n * 256);
            nk1 = *(const bf16x8*)(kbase + (size_t)(t0n + 16) * 256);
            nv0 = *(const bf16x8*)(vbase + t0n);
            nv1 = *(const bf16x8*)(vbase + 16 * 224 + t0n);
        }
        bool mask0 = (t0 + lr)      >= 196;
        bool mask1 = (t0 + 16 + lr) >= 196;
        #pragma unroll
        for (int mt = 0; mt < 7; ++mt) {
            f32x4 z = {0.f,0.f,0.f,0.f};
            f32x4 s0 = MFMA(qf[mt], ck0, z);
            f32x4 s1 = MFMA(qf[mt], ck1, z);
            #pragma unroll
            for (int r = 0; r < 4; ++r) {
                float p0 = mask0 ? 0.f : __expf(s0[r]);
                float p1 = mask1 ? 0.f : __expf(s1[r]);
                Pw[(lg * 4 + r) * 40 + lr]      = f2bf(p0);
                Pw[(lg * 4 + r) * 40 + 16 + lr] = f2bf(p1);
            }
            bf16x8 pf = *(const bf16x8*)(&Pw[lr * 40 + lg * 8]);
            o_acc[mt][0] = MFMA(pf, cv0, o_acc[mt][0]);
            o_acc[mt][1] = MFMA(pf, cv1, o_acc[mt][1]);
            l_acc[mt]    = MFMA(pf, ones, l_acc[mt]);
        }
        ck0 = nk0; ck1 = nk1; cv0 = nv0; cv1 = nv1;
    }

    __syncthreads();   // all waves done with Pp before O2 overlay
    // normalized O -> OL[112][264] (wave-private columns)
    #pragma unroll
    for (int mt = 0; mt < 7; ++mt) {
        #pragma unroll
        for (int r = 0; r < 4; ++r) {
            float inv = 1.f / l_acc[mt][r];
            int srow = mt * 16 + lg * 4 + r;
            OL[srow * 264 + w * 32 + lr]      = f2bf(o_acc[mt][0][r] * inv);
            OL[srow * 264 + w * 32 + 16 + lr] = f2bf(o_acc[mt][1][r] * inv);
        }
    }
    __syncthreads();

    // o2 = OL @ wo_c^T + bo_c
    {
        f32x4 a2[7][2];
        #pragma unroll
        for (int mt = 0; mt < 7; ++mt)
            #pragma unroll
            for (int nt = 0; nt < 2; ++nt) { f32x4 z = {0.f,0.f,0.f,0.f}; a2[mt][nt] = z; }
        for (int ks = 0; ks < 8; ++ks) {
            int c0 = ks * 32;
            bf16x8 bw[2];
            #pragma unroll
            for (int nt = 0; nt < 2; ++nt)
                bw[nt] = *(const bf16x8*)(Wall + (size_t)(1792 + w * 32 + nt * 16 + lr) * 256 + c0 + lg * 8);
            #pragma unroll
            for (int mt = 0; mt < 7; ++mt) {
                bf16x8 af = *(const bf16x8*)(&OL[(mt * 16 + lr) * 264 + c0 + lg * 8]);
                a2[mt][0] = MFMA(af, bw[0], a2[mt][0]);
                a2[mt][1] = MFMA(af, bw[1], a2[mt][1]);
            }
        }
        #pragma unroll
        for (int mt = 0; mt < 7; ++mt)
            #pragma unroll
            for (int nt = 0; nt < 2; ++nt) {
                float bias = Ball[1792 + w * 32 + nt * 16 + lr];
                #pragma unroll
                for (int r = 0; r < 4; ++r) {
                    int srow = mt * 16 + lg * 4 + r;
                    O2[srow * 264 + w * 32 + nt * 16 + lr] = f2bf(a2[mt][nt][r] + bias);
                }
            }
    }
    __syncthreads();

    // h1 = relu(O2 @ w1^T + b1) -> OL
    {
        f32x4 a2[7][2];
        #pragma unroll
        for (int mt = 0; mt < 7; ++mt)
            #pragma unroll
            for (int nt = 0; nt < 2; ++nt) { f32x4 z = {0.f,0.f,0.f,0.f}; a2[mt][nt] = z; }
        for (int ks = 0; ks < 8; ++ks) {
            int c0 = ks * 32;
            bf16x8 bw[2];
            #pragma unroll
            for (int nt = 0; nt < 2; ++nt)
                bw[nt] = *(const bf16x8*)(Wall + (size_t)(2048 + w * 32 + nt * 16 + lr) * 256 + c0 + lg * 8);
            #pragma unroll
            for (int mt = 0; mt < 7; ++mt) {
                bf16x8 af = *(const bf16x8*)(&O2[(mt * 16 + lr) * 264 + c0 + lg * 8]);
                a2[mt][0] = MFMA(af, bw[0], a2[mt][0]);
                a2[mt][1] = MFMA(af, bw[1], a2[mt][1]);
            }
        }
        __syncthreads();   // all OL reads (oproj phase) complete before overwrite
        #pragma unroll
        for (int mt = 0; mt < 7; ++mt)
            #pragma unroll
            for (int nt = 0; nt < 2; ++nt) {
                float bias = Ball[2048 + w * 32 + nt * 16 + lr];
                #pragma unroll
                for (int r = 0; r < 4; ++r) {
                    int srow = mt * 16 + lg * 4 + r;
                    float v = a2[mt][nt][r] + bias;
                    v = v > 0.f ? v : 0.f;
                    OL[srow * 264 + w * 32 + nt * 16 + lr] = f2bf(v);
                }
            }
    }
    __syncthreads();

    // hbar[c] = mean_s<100 h1[s][c];  score partials from O2
    if (tid < 256) {
        float s = 0.f;
        for (int srow = 0; srow < 100; ++srow) s += bf2f(OL[srow * 264 + tid]);
        hbar[tid] = s * 0.01f;
    }
    if (tid < 100) {
        float s = 0.f;
        for (int c2 = 0; c2 < 256; ++c2)
            s += bf2f(O2[tid * 264 + c2]) * bf2f(Wall[(size_t)2336 * 256 + c2]);
        s += Ball[2336];
        scb[tid] = 1.f / (1.f + __expf(-s));
    }
    __syncthreads();
    if (tid < 32) {
        float s = 0.f;
        for (int c2 = 0; c2 < 256; ++c2)
            s += hbar[c2] * bf2f(Wall[(size_t)(2304 + tid) * 256 + c2]);
        s += Ball[2304 + tid];
        outp[(size_t)n * 32 + tid] = s;
    }
    if (tid == 64) {
        float s = 0.f;
        for (int i2 = 0; i2 < 100; ++i2) s += scb[i2];
        outp[16384 + n] = s * 0.01f;
    }
}

// ---------------------------------------------------------------------------
extern "C" void kernel_launch(void* const* d_in, const int* in_sizes, int n_in,
                              void* d_out, int out_size, void* d_ws, size_t ws_size,
                              hipStream_t stream)
{
    const float* features = (const float*)d_in[0];
    const float* qfeat    = (const float*)d_in[1];
    char* ws = (char*)d_ws;

    ushort* wbf  = (ushort*)ws;                    //  2337*256 bf16
    float*  bias = (float*)(ws + 1196544);         //  2337 f32
    ushort* qkv  = (ushort*)(ws + 1206016);        //  800*768
    ushort* sav  = (ushort*)(ws + 2434816);        //  800*256
    ushort* osb  = (ushort*)(ws + 2844416);        //  800*256
    ushort* qcp  = (ushort*)(ws + 3254016);        //  8*8*112*32
    ushort* kvb  = (ushort*)(ws + 3712768);

    prep_kernel<<<dim3(512), dim3(256), 0, stream>>>(
        (const float*)d_in[2], (const float*)d_in[3], (const float*)d_in[4],
        (const float*)d_in[8], (const float*)d_in[10], (const float*)d_in[11],
        (const float*)d_in[12], (const float*)d_in[16], (const float*)d_in[18],
        (const float*)d_in[20], (const float*)d_in[22],
        (const float*)d_in[5], (const float*)d_in[6], (const float*)d_in[7],
        (const float*)d_in[9], (const float*)d_in[13], (const float*)d_in[14],
        (const float*)d_in[15], (const float*)d_in[17], (const float*)d_in[19],
        (const float*)d_in[21], (const float*)d_in[23],
        wbf, bias, qcp);

    // self-attention chain
    gemm_rows<1, 100, 0><<<dim3(13, 6), dim3(256), 0, stream>>>(
        qfeat, wbf, bias, qkv, 800, 0, 0, 768);
    self_attn<<<dim3(64), dim3(128), 0, stream>>>(qkv, sav);
    gemm_rows<0, 1, 0><<<dim3(13, 2), dim3(256), 0, stream>>>(
        sav, wbf, bias, osb, 800, 768, 768, 256);
    gemm_rows<0, 1, 1><<<dim3(13, 2), dim3(256), 0, stream>>>(
        osb, wbf, bias, qcp, 800, 1024, 1024, 0);

    // cross-attention, pass-split on workspace budget
    const size_t per_n = 229376;               // bytes of kc+vc per proposal
    long avail = (long)ws_size - 3712768L;
    int Np = 512;
    if (avail < (long)(per_n * 512)) {
        Np = (int)(avail / (long)per_n);
        if (Np < 1) Np = 1;
    }
    ushort* kcb = kvb;                                   // [Np][224][256]
    ushort* vcb = kvb + (size_t)Np * 224 * 256;          // [Np][256][224]
    float* outp = (float*)d_out;
    for (int n0 = 0; n0 < 512; n0 += Np) {
        int cnt = (512 - n0 < Np) ? (512 - n0) : Np;
        kvproj<<<dim3(cnt, 2), dim3(512), 0, stream>>>(features, wbf, bias, kcb, vcb, n0);
        attn_fuse<<<dim3(cnt), dim3(512), 0, stream>>>(qcp, kcb, vcb, wbf, bias, outp, n0);
    }
}

// Round 10
// 276.796 us; speedup vs baseline: 1.4089x; 1.3342x over previous
//
#include <hip/hip_runtime.h>
#include <hip/hip_bf16.h>

// ---------------------------------------------------------------------------
// PolygonPredictionLayer: B=8,P=64,N=512,T=196(->224),S=100(->112),C=256,H=8,dh=32
// R10: kvproj v7 -- R5's proven register shape (weights persistent af[4][8],
//   AGPR-able) + raw-f32 LDS staging Fs[256][114] (float2 copies, no cvt/no
//   transpose on store; cvt_pk on read) + per-t-tile writeout (acc transient).
//   Grid (n,2) t-halves, ONE barrier. attn_fuse v2 (R9): barrier-free main
//   loop, K/V frags direct from global (kc t-major / vc c-major).
// ---------------------------------------------------------------------------

typedef __attribute__((ext_vector_type(8))) short bf16x8;
typedef __attribute__((ext_vector_type(4))) float f32x4;

__device__ __forceinline__ float bf2f(ushort u) {
    union { float f; uint u32; } v; v.u32 = ((uint)u) << 16; return v.f;
}
__device__ __forceinline__ ushort f2bf(float f) {
    union { float f; uint u; } v; v.f = f;
    uint r = v.u + 0x7FFF + ((v.u >> 16) & 1);
    return (ushort)(r >> 16);
}
__device__ __forceinline__ uint pk2(float a, float b) {
    __hip_bfloat162 h = __float22bfloat162_rn(make_float2(a, b));
    union { __hip_bfloat162 h2; uint u; } c; c.h2 = h; return c.u;
}
__device__ __forceinline__ f32x4 MFMA(bf16x8 a, bf16x8 b, f32x4 c) {
    return __builtin_amdgcn_mfma_f32_16x16x32_bf16(a, b, c, 0, 0, 0);
}

#define SCALE_DH 0.17677669529663687f  // 1/sqrt(32)

// ---------------- prep: weights+biases -> ws tables, qcp zero ---------------
#define TOTALW (2337 * 256)
#define QCPN   (8 * 8 * 112 * 32)
#define NBIAS  2337

__global__ void prep_kernel(const float* w0, const float* w1_, const float* w2_,
                            const float* w3, const float* w4, const float* w5,
                            const float* w6, const float* w7, const float* w8,
                            const float* w9, const float* w10,
                            const float* b0, const float* b1_, const float* b2_,
                            const float* b3, const float* b4, const float* b5,
                            const float* b6, const float* b7, const float* b8,
                            const float* b9, const float* b10,
                            ushort* wbf, float* bias, ushort* qcp)
{
    for (size_t i = blockIdx.x * blockDim.x + threadIdx.x;
         i < (size_t)TOTALW + QCPN + NBIAS; i += (size_t)gridDim.x * blockDim.x) {
        if (i < TOTALW) {
            int row = (int)(i >> 8), col = (int)(i & 255);
            const float* sp; int base;
            if      (row < 256)  { sp = w0;  base = 0; }
            else if (row < 512)  { sp = w1_; base = 256; }
            else if (row < 768)  { sp = w2_; base = 512; }
            else if (row < 1024) { sp = w3;  base = 768; }
            else if (row < 1280) { sp = w4;  base = 1024; }
            else if (row < 1536) { sp = w5;  base = 1280; }
            else if (row < 1792) { sp = w6;  base = 1536; }
            else if (row < 2048) { sp = w7;  base = 1792; }
            else if (row < 2304) { sp = w8;  base = 2048; }
            else if (row < 2336) { sp = w9;  base = 2304; }
            else                 { sp = w10; base = 2336; }
            wbf[i] = f2bf(sp[(size_t)(row - base) * 256 + col]);
        } else if (i < (size_t)TOTALW + QCPN) {
            qcp[i - TOTALW] = 0;
        } else {
            int idx = (int)(i - TOTALW - QCPN);
            const float* sp; int base;
            if      (idx < 256)  { sp = b0;  base = 0; }
            else if (idx < 512)  { sp = b1_; base = 256; }
            else if (idx < 768)  { sp = b2_; base = 512; }
            else if (idx < 1024) { sp = b3;  base = 768; }
            else if (idx < 1280) { sp = b4;  base = 1024; }
            else if (idx < 1536) { sp = b5;  base = 1280; }
            else if (idx < 1792) { sp = b6;  base = 1536; }
            else if (idx < 2048) { sp = b7;  base = 1792; }
            else if (idx < 2304) { sp = b8;  base = 2048; }
            else if (idx < 2336) { sp = b9;  base = 2304; }
            else                 { sp = b10; base = 2336; }
            bias[idx] = sp[idx - base];
        }
    }
}

// ---------------- generic small GEMM: out = A @ W^T + bias -----------------
template<int ASRC, int GS, int EPI>
__global__ __launch_bounds__(256)
void gemm_rows(const void* Aptr, const ushort* Wall, const float* Ball,
               ushort* Out, int M, int Wrow0, int Brow0, int ldo)
{
    __shared__ ushort As[64 * 40];
    __shared__ ushort Bs[128 * 40];
    int tid = threadIdx.x;
    int lane = tid & 63, w = tid >> 6;
    int lr = lane & 15, lg = lane >> 4;
    int r0 = blockIdx.x * 64;
    int j0 = blockIdx.y * 128;

    f32x4 acc[4][2];
    #pragma unroll
    for (int mt = 0; mt < 4; ++mt)
        #pragma unroll
        for (int nt = 0; nt < 2; ++nt) { f32x4 z = {0.f,0.f,0.f,0.f}; acc[mt][nt] = z; }

    for (int ks = 0; ks < 8; ++ks) {
        int c0 = ks * 32;
        {
            int i = tid >> 2, q = tid & 3;
            int r = r0 + i;
            if (ASRC == 0) {
                uint4 v = make_uint4(0u,0u,0u,0u);
                if (r < M) v = *(const uint4*)((const ushort*)Aptr + (size_t)r * 256 + c0 + q * 8);
                *(uint4*)(&As[i * 40 + q * 8]) = v;
            } else {
                uint u[4] = {0u,0u,0u,0u};
                if (r < M) {
                    int g = r / GS, o = r - g * GS;
                    const float* src = (const float*)Aptr + (size_t)g * 256 * GS + o;
                    #pragma unroll
                    for (int k2 = 0; k2 < 4; ++k2) {
                        ushort a0 = f2bf(src[(size_t)(c0 + q * 8 + 2 * k2)     * GS]);
                        ushort a1 = f2bf(src[(size_t)(c0 + q * 8 + 2 * k2 + 1) * GS]);
                        u[k2] = (uint)a0 | ((uint)a1 << 16);
                    }
                }
                *(uint4*)(&As[i * 40 + q * 8]) = make_uint4(u[0], u[1], u[2], u[3]);
            }
        }
        {
            int jj = tid >> 1, half = tid & 1;
            const ushort* src = Wall + (size_t)(Wrow0 + j0 + jj) * 256 + c0 + half * 16;
            ushort* dst = &Bs[jj * 40 + half * 16];
            *(uint4*)(dst)     = *(const uint4*)(src);
            *(uint4*)(dst + 8) = *(const uint4*)(src + 8);
        }
        __syncthreads();
        bf16x8 bfr[2];
        #pragma unroll
        for (int nt = 0; nt < 2; ++nt)
            bfr[nt] = *(const bf16x8*)(&Bs[(w * 32 + nt * 16 + lr) * 40 + lg * 8]);
        #pragma unroll
        for (int mt = 0; mt < 4; ++mt) {
            bf16x8 afr = *(const bf16x8*)(&As[(mt * 16 + lr) * 40 + lg * 8]);
            acc[mt][0] = MFMA(afr, bfr[0], acc[mt][0]);
            acc[mt][1] = MFMA(afr, bfr[1], acc[mt][1]);
        }
        __syncthreads();
    }
    #pragma unroll
    for (int mt = 0; mt < 4; ++mt) {
        #pragma unroll
        for (int nt = 0; nt < 2; ++nt) {
            int jc = j0 + w * 32 + nt * 16 + lr;
            float bias = Ball[Brow0 + jc];
            #pragma unroll
            for (int rg = 0; rg < 4; ++rg) {
                int r = r0 + mt * 16 + lg * 4 + rg;
                if (r >= M) continue;
                float vv = acc[mt][nt][rg] + bias;
                if (EPI == 0) {
                    Out[(size_t)r * ldo + jc] = f2bf(vv);
                } else {
                    int b = r / 100, s = r - b * 100;
                    int h = jc >> 5, d = jc & 31;
                    Out[(((size_t)(b * 8 + h)) * 112 + s) * 32 + d] = f2bf(vv * SCALE_DH);
                }
            }
        }
    }
}

// ---------------- self-attention (tiny, VALU) ------------------------------
__global__ __launch_bounds__(128)
void self_attn(const ushort* qkv, ushort* sav)
{
    __shared__ float kls[100][33];
    __shared__ float vls[100][33];
    __shared__ float sls[100][101];
    int bh = blockIdx.x; int b = bh >> 3, h = bh & 7;
    int tid = threadIdx.x;
    for (int idx = tid; idx < 100 * 32; idx += 128) {
        int t = idx >> 5, d = idx & 31;
        kls[t][d] = bf2f(qkv[((size_t)(b * 100 + t)) * 768 + 256 + h * 32 + d]);
        vls[t][d] = bf2f(qkv[((size_t)(b * 100 + t)) * 768 + 512 + h * 32 + d]);
    }
    __syncthreads();
    if (tid < 100) {
        int s = tid;
        float q[32];
        #pragma unroll
        for (int d = 0; d < 32; ++d)
            q[d] = bf2f(qkv[((size_t)(b * 100 + s)) * 768 + h * 32 + d]) * SCALE_DH;
        float mx = -1e30f;
        for (int t = 0; t < 100; ++t) {
            float sc = 0.f;
            #pragma unroll
            for (int d = 0; d < 32; ++d) sc += q[d] * kls[t][d];
            sls[s][t] = sc; mx = fmaxf(mx, sc);
        }
        float sum = 0.f;
        for (int t = 0; t < 100; ++t) {
            float p = __expf(sls[s][t] - mx);
            sls[s][t] = p; sum += p;
        }
        float inv = 1.f / sum;
        float acc2[32];
        #pragma unroll
        for (int d = 0; d < 32; ++d) acc2[d] = 0.f;
        for (int t = 0; t < 100; ++t) {
            float pv = sls[s][t];
            #pragma unroll
            for (int d = 0; d < 32; ++d) acc2[d] += pv * vls[t][d];
        }
        #pragma unroll
        for (int d = 0; d < 32; ++d)
            sav[((size_t)(b * 100 + s)) * 256 + h * 32 + d] = f2bf(acc2[d] * inv);
    }
}

// ---------------- kvproj v7: kc[n][224][256] t-major, vc[n][256][224] ------
// grid (cnt, 2 th), block 512 (8 waves). A = weights persistent af[4][8]
// (R5's proven shape). B = features RAW f32 in LDS Fs[256][114] (float2
// staging, no conversion, no transpose); cvt_pk on read. ONE barrier.
// acc transient per t-tile. Wave w owns couts [32w,32w+32) of K and V.
__global__ __launch_bounds__(512, 2)
void kvproj(const float* features, const ushort* Wall, const float* Ball,
            ushort* kc, ushort* vc, int n_base)
{
    __shared__ float Fs[256 * 114];
    int tid = threadIdx.x;
    int lane = tid & 63, w = tid >> 6;
    int lr = lane & 15, lg = lane >> 4;
    int nl = blockIdx.x;
    int n  = n_base + nl;
    int th = blockIdx.y;
    int t0b = th * 112;
    const float* fb = features + (size_t)n * 256 * 196;

    // persistent weight A-frags: af[m][ks]; m 0,1 = K (nt0/1), m 2,3 = V
    // A[row=cout_local=lr][k=c=ks*32+lg*8+j]
    bf16x8 af[4][8];
    #pragma unroll
    for (int m = 0; m < 4; ++m) {
        int row = ((m < 2) ? 1280 : 1536) + w * 32 + (m & 1) * 16 + lr;
        #pragma unroll
        for (int ks = 0; ks < 8; ++ks)
            af[m][ks] = *(const bf16x8*)(Wall + (size_t)row * 256 + ks * 32 + lg * 8);
    }

    // stage Fs[c][tq] = fb[c][t0b+tq] raw f32; 256c x 56 float2, 28/thread.
    // t always even; max valid t=194 reads {194,195} -- never straddles row end.
    #pragma unroll
    for (int i = 0; i < 28; ++i) {
        int idx = i * 512 + tid;
        int c = idx / 56, tq = (idx - c * 56) * 2;
        int t = t0b + tq;
        float2 v = make_float2(0.f, 0.f);
        if (t < 196) v = *(const float2*)(fb + (size_t)c * 196 + t);
        *(float2*)(&Fs[c * 114 + tq]) = v;
    }
    __syncthreads();   // the only barrier

    for (int tt = 0; tt < 7; ++tt) {
        f32x4 acc[4];
        #pragma unroll
        for (int m = 0; m < 4; ++m) { f32x4 z = {0.f,0.f,0.f,0.f}; acc[m] = z; }
        #pragma unroll
        for (int ks = 0; ks < 8; ++ks) {
            // B[k=c][col=t]: 8 rows of Fs (stride 114) at col tt*16+lr
            const float* bp = &Fs[(ks * 32 + lg * 8) * 114 + tt * 16 + lr];
            union { uint4 q; bf16x8 v; } bu;
            bu.q.x = pk2(bp[0],   bp[114]);
            bu.q.y = pk2(bp[228], bp[342]);
            bu.q.z = pk2(bp[456], bp[570]);
            bu.q.w = pk2(bp[684], bp[798]);
            #pragma unroll
            for (int m = 0; m < 4; ++m)
                acc[m] = MFMA(af[m][ks], bu.v, acc[m]);
        }
        // writeout: D[row=cout_local=(m&1)*16+lg*4+rg][col=t=lr]
        int tloc = t0b + tt * 16 + lr;
        #pragma unroll
        for (int m = 0; m < 4; ++m) {
            int cout0 = w * 32 + (m & 1) * 16 + lg * 4;
            if (m < 2) {   // kc t-major: 4 consecutive couts -> ushort4
                float4 bk4 = *(const float4*)(Ball + 1280 + cout0);
                ushort4 o;
                o.x = f2bf(acc[m][0] + bk4.x);
                o.y = f2bf(acc[m][1] + bk4.y);
                o.z = f2bf(acc[m][2] + bk4.z);
                o.w = f2bf(acc[m][3] + bk4.w);
                *(ushort4*)(kc + ((size_t)nl * 224 + tloc) * 256 + cout0) = o;
            } else {       // vc c-major: scalar per cout (L2 merges)
                float4 bv4 = *(const float4*)(Ball + 1536 + cout0);
                vc[((size_t)nl * 256 + cout0 + 0) * 224 + tloc] = f2bf(acc[m][0] + bv4.x);
                vc[((size_t)nl * 256 + cout0 + 1) * 224 + tloc] = f2bf(acc[m][1] + bv4.y);
                vc[((size_t)nl * 256 + cout0 + 2) * 224 + tloc] = f2bf(acc[m][2] + bv4.z);
                vc[((size_t)nl * 256 + cout0 + 3) * 224 + tloc] = f2bf(acc[m][3] + bv4.w);
            }
        }
    }
}

// ---------------- attn_fuse v2: barrier-free main loop ---------------------
// block 512 (8 waves, wave = head). K/V fragments loaded DIRECTLY from global
// (kc t-major, vc c-major are frag-contiguous); double-buffered in registers.
// LDS: Pp[8][16][40] @71680 (main loop only). Epilogue overlay: OL[112][264]
// @0 | hbar @59392 | scb @60416 | O2[112][264] @71680.
__global__ __launch_bounds__(512, 2)
void attn_fuse(const ushort* qcp, const ushort* kc, const ushort* vc,
               const ushort* Wall, const float* Ball, float* outp, int n_base)
{
    __shared__ char smem[130816];
    ushort* OL  = (ushort*)smem;
    float* hbar = (float*)(smem + 59392);
    float* scb  = (float*)(smem + 60416);
    ushort* O2  = (ushort*)(smem + 71680);
    ushort* Pp  = (ushort*)(smem + 71680);   // disjoint in time from O2

    int tid = threadIdx.x;
    int lane = tid & 63; int w = tid >> 6;             // w = head
    int lr = lane & 15, lg = lane >> 4;
    int nl = blockIdx.x; int n = n_base + nl;
    int b = n >> 6;
    const ushort* kcn = kc + (size_t)nl * 224 * 256;
    const ushort* vcn = vc + (size_t)nl * 256 * 224;
    ushort* Pw = Pp + w * 640;                          // [16 s][40 t]

    bf16x8 qf[7];
    #pragma unroll
    for (int mt = 0; mt < 7; ++mt)
        qf[mt] = *(const bf16x8*)(qcp + ((((size_t)(b * 8 + w)) * 112 + mt * 16 + lr) * 32 + lg * 8));

    bf16x8 ones;
    #pragma unroll
    for (int j = 0; j < 8; ++j) ones[j] = (short)0x3F80;

    f32x4 o_acc[7][2], l_acc[7];
    #pragma unroll
    for (int mt = 0; mt < 7; ++mt) {
        f32x4 z = {0.f,0.f,0.f,0.f};
        o_acc[mt][0] = z; o_acc[mt][1] = z; l_acc[mt] = z;
    }

    // fragment addresses:
    //  bk(sub): kcn[(t0 + sub*16 + lr)*256 + w*32 + lg*8]   (K[t][d], 8 contig d)
    //  bv(sub): vcn[(w*32 + sub*16 + lr)*224 + t0 + lg*8]   (V^T[c][t], 8 contig t)
    const ushort* kbase = kcn + (size_t)lr * 256 + w * 32 + lg * 8;
    const ushort* vbase = vcn + ((size_t)(w * 32 + lr)) * 224 + lg * 8;

    bf16x8 ck0, ck1, cv0, cv1;
    ck0 = *(const bf16x8*)(kbase);
    ck1 = *(const bf16x8*)(kbase + 16 * 256);
    cv0 = *(const bf16x8*)(vbase);
    cv1 = *(const bf16x8*)(vbase + 16 * 224);

    for (int ch = 0; ch < 7; ++ch) {
        int t0 = ch * 32;
        bf16x8 nk0, nk1, nv0, nv1;
        if (ch < 6) {   // T14: next chunk's fragments issued before compute
            int t0n = t0 + 32;
            nk0 = *(const bf16x8*)(kbase + (size_t)t0n * 256);
            nk1 = *(const bf16x8*)(kbase + (size_t)(t0n + 16) * 256);
            nv0 = *(const bf16x8*)(vbase + t0n);
            nv1 = *(const bf16x8*)(vbase + 16 * 224 + t0n);
        }
        bool mask0 = (t0 + lr)      >= 196;
        bool mask1 = (t0 + 16 + lr) >= 196;
        #pragma unroll
        for (int mt = 0; mt < 7; ++mt) {
            f32x4 z = {0.f,0.f,0.f,0.f};
            f32x4 s0 = MFMA(qf[mt], ck0, z);
            f32x4 s1 = MFMA(qf[mt], ck1, z);
            #pragma unroll
            for (int r = 0; r < 4; ++r) {
                float p0 = mask0 ? 0.f : __expf(s0[r]);
                float p1 = mask1 ? 0.f : __expf(s1[r]);
                Pw[(lg * 4 + r) * 40 + lr]      = f2bf(p0);
                Pw[(lg * 4 + r) * 40 + 16 + lr] = f2bf(p1);
            }
            bf16x8 pf = *(const bf16x8*)(&Pw[lr * 40 + lg * 8]);
            o_acc[mt][0] = MFMA(pf, cv0, o_acc[mt][0]);
            o_acc[mt][1] = MFMA(pf, cv1, o_acc[mt][1]);
            l_acc[mt]    = MFMA(pf, ones, l_acc[mt]);
        }
        ck0 = nk0; ck1 = nk1; cv0 = nv0; cv1 = nv1;
    }

    __syncthreads();   // all waves done with Pp before O2 overlay
    // normalized O -> OL[112][264] (wave-private columns)
    #pragma unroll
    for (int mt = 0; mt < 7; ++mt) {
        #pragma unroll
        for (int r = 0; r < 4; ++r) {
            float inv = 1.f / l_acc[mt][r];
            int srow = mt * 16 + lg * 4 + r;
            OL[srow * 264 + w * 32 + lr]      = f2bf(o_acc[mt][0][r] * inv);
            OL[srow * 264 + w * 32 + 16 + lr] = f2bf(o_acc[mt][1][r] * inv);
        }
    }
    __syncthreads();

    // o2 = OL @ wo_c^T + bo_c
    {
        f32x4 a2[7][2];
        #pragma unroll
        for (int mt = 0; mt < 7; ++mt)
            #pragma unroll
            for (int nt = 0; nt < 2; ++nt) { f32x4 z = {0.f,0.f,0.f,0.f}; a2[mt][nt] = z; }
        for (int ks = 0; ks < 8; ++ks) {
            int c0 = ks * 32;
            bf16x8 bw[2];
            #pragma unroll
            for (int nt = 0; nt < 2; ++nt)
                bw[nt] = *(const bf16x8*)(Wall + (size_t)(1792 + w * 32 + nt * 16 + lr) * 256 + c0 + lg * 8);
            #pragma unroll
            for (int mt = 0; mt < 7; ++mt) {
                bf16x8 af = *(const bf16x8*)(&OL[(mt * 16 + lr) * 264 + c0 + lg * 8]);
                a2[mt][0] = MFMA(af, bw[0], a2[mt][0]);
                a2[mt][1] = MFMA(af, bw[1], a2[mt][1]);
            }
        }
        #pragma unroll
        for (int mt = 0; mt < 7; ++mt)
            #pragma unroll
            for (int nt = 0; nt < 2; ++nt) {
                float bias = Ball[1792 + w * 32 + nt * 16 + lr];
                #pragma unroll
                for (int r = 0; r < 4; ++r) {
                    int srow = mt * 16 + lg * 4 + r;
                    O2[srow * 264 + w * 32 + nt * 16 + lr] = f2bf(a2[mt][nt][r] + bias);
                }
            }
    }
    __syncthreads();

    // h1 = relu(O2 @ w1^T + b1) -> OL
    {
        f32x4 a2[7][2];
        #pragma unroll
        for (int mt = 0; mt < 7; ++mt)
            #pragma unroll
            for (int nt = 0; nt < 2; ++nt) { f32x4 z = {0.f,0.f,0.f,0.f}; a2[mt][nt] = z; }
        for (int ks = 0; ks < 8; ++ks) {
            int c0 = ks * 32;
            bf16x8 bw[2];
            #pragma unroll
            for (int nt = 0; nt < 2; ++nt)
                bw[nt] = *(const bf16x8*)(Wall + (size_t)(2048 + w * 32 + nt * 16 + lr) * 256 + c0 + lg * 8);
            #pragma unroll
            for (int mt = 0; mt < 7; ++mt) {
                bf16x8 af = *(const bf16x8*)(&O2[(mt * 16 + lr) * 264 + c0 + lg * 8]);
                a2[mt][0] = MFMA(af, bw[0], a2[mt][0]);
                a2[mt][1] = MFMA(af, bw[1], a2[mt][1]);
            }
        }
        __syncthreads();   // all OL reads (oproj phase) complete before overwrite
        #pragma unroll
        for (int mt = 0; mt < 7; ++mt)
            #pragma unroll
            for (int nt = 0; nt < 2; ++nt) {
                float bias = Ball[2048 + w * 32 + nt * 16 + lr];
                #pragma unroll
                for (int r = 0; r < 4; ++r) {
                    int srow = mt * 16 + lg * 4 + r;
                    float v = a2[mt][nt][r] + bias;
                    v = v > 0.f ? v : 0.f;
                    OL[srow * 264 + w * 32 + nt * 16 + lr] = f2bf(v);
                }
            }
    }
    __syncthreads();

    // hbar[c] = mean_s<100 h1[s][c];  score partials from O2
    if (tid < 256) {
        float s = 0.f;
        for (int srow = 0; srow < 100; ++srow) s += bf2f(OL[srow * 264 + tid]);
        hbar[tid] = s * 0.01f;
    }
    if (tid < 100) {
        float s = 0.f;
        for (int c2 = 0; c2 < 256; ++c2)
            s += bf2f(O2[tid * 264 + c2]) * bf2f(Wall[(size_t)2336 * 256 + c2]);
        s += Ball[2336];
        scb[tid] = 1.f / (1.f + __expf(-s));
    }
    __syncthreads();
    if (tid < 32) {
        float s = 0.f;
        for (int c2 = 0; c2 < 256; ++c2)
            s += hbar[c2] * bf2f(Wall[(size_t)(2304 + tid) * 256 + c2]);
        s += Ball[2304 + tid];
        outp[(size_t)n * 32 + tid] = s;
    }
    if (tid == 64) {
        float s = 0.f;
        for (int i2 = 0; i2 < 100; ++i2) s += scb[i2];
        outp[16384 + n] = s * 0.01f;
    }
}

// ---------------------------------------------------------------------------
extern "C" void kernel_launch(void* const* d_in, const int* in_sizes, int n_in,
                              void* d_out, int out_size, void* d_ws, size_t ws_size,
                              hipStream_t stream)
{
    const float* features = (const float*)d_in[0];
    const float* qfeat    = (const float*)d_in[1];
    char* ws = (char*)d_ws;

    ushort* wbf  = (ushort*)ws;                    //  2337*256 bf16
    float*  bias = (float*)(ws + 1196544);         //  2337 f32
    ushort* qkv  = (ushort*)(ws + 1206016);        //  800*768
    ushort* sav  = (ushort*)(ws + 2434816);        //  800*256
    ushort* osb  = (ushort*)(ws + 2844416);        //  800*256
    ushort* qcp  = (ushort*)(ws + 3254016);        //  8*8*112*32
    ushort* kvb  = (ushort*)(ws + 3712768);

    prep_kernel<<<dim3(512), dim3(256), 0, stream>>>(
        (const float*)d_in[2], (const float*)d_in[3], (const float*)d_in[4],
        (const float*)d_in[8], (const float*)d_in[10], (const float*)d_in[11],
        (const float*)d_in[12], (const float*)d_in[16], (const float*)d_in[18],
        (const float*)d_in[20], (const float*)d_in[22],
        (const float*)d_in[5], (const float*)d_in[6], (const float*)d_in[7],
        (const float*)d_in[9], (const float*)d_in[13], (const float*)d_in[14],
        (const float*)d_in[15], (const float*)d_in[17], (const float*)d_in[19],
        (const float*)d_in[21], (const float*)d_in[23],
        wbf, bias, qcp);

    // self-attention chain
    gemm_rows<1, 100, 0><<<dim3(13, 6), dim3(256), 0, stream>>>(
        qfeat, wbf, bias, qkv, 800, 0, 0, 768);
    self_attn<<<dim3(64), dim3(128), 0, stream>>>(qkv, sav);
    gemm_rows<0, 1, 0><<<dim3(13, 2), dim3(256), 0, stream>>>(
        sav, wbf, bias, osb, 800, 768, 768, 256);
    gemm_rows<0, 1, 1><<<dim3(13, 2), dim3(256), 0, stream>>>(
        osb, wbf, bias, qcp, 800, 1024, 1024, 0);

    // cross-attention, pass-split on workspace budget
    const size_t per_n = 229376;               // bytes of kc+vc per proposal
    long avail = (long)ws_size - 3712768L;
    int Np = 512;
    if (avail < (long)(per_n * 512)) {
        Np = (int)(avail / (long)per_n);
        if (Np < 1) Np = 1;
    }
    ushort* kcb = kvb;                                   // [Np][224][256]
    ushort* vcb = kvb + (size_t)Np * 224 * 256;          // [Np][256][224]
    float* outp = (float*)d_out;
    for (int n0 = 0; n0 < 512; n0 += Np) {
        int cnt = (512 - n0 < Np) ? (512 - n0) : Np;
        kvproj<<<dim3(cnt, 2), dim3(512), 0, stream>>>(features, wbf, bias, kcb, vcb, n0);
        attn_fuse<<<dim3(cnt), dim3(512), 0, stream>>>(qcp, kcb, vcb, wbf, bias, outp, n0);
    }
}